// Round 16
// baseline (74.768 us; speedup 1.0000x reference)
//
#include <hip/hip_runtime.h>
#include <stdint.h>

// TopKLayer quirky sparse_hw: per row (3136 elems), t = spatial index of the
// k-th largest |x| (k=313, ties ascending index); keep the t smallest-|x|
// elements (stable). NT=128 block per row, ROW STAGED IN LDS (frees the
// register file -> residency LDS-bound at ~9 blocks/CU, 2.25x the reg-row's
// 4). R12's lean flow otherwise: fused load+hist, packed-u16 padded 2048-bin
// hist, cpk[8] register CDF (lives across both locates; hist region is then
// overlaid by cand/hc/tiny), O(1) locate, wave0 finish.

#define HW    3136
#define NW4   784        // HW/4
#define NT    128
#define KSEL  313u
#define CAP   320u       // candidate bin capacity (stat max ~190)
#define CAP2  64u        // tie-set capacity
#define M31   0x7fffffffu
#define SENT  0xFFFFFFFFu

// LDS layout (words)
#define O_X    0         // 3136 row words (784 uint4)
#define O_H    3136      // 1088 = 1024 packed-u16 words + pad every 16
#define O_CAND 3136      // overlay (hist dead after CDF pull): 320
#define O_HC   3520      // 256
#define O_TINY 3776      // 64
#define LDSW   4224      // 16896 B

__device__ __forceinline__ unsigned wscan_incl(unsigned v) {
    const int lane = threadIdx.x & 63;
#pragma unroll
    for (int d = 1; d < 64; d <<= 1) {
        unsigned o = __shfl_up(v, d, 64);
        if (lane >= d) v += o;
    }
    return v;
}

__device__ __forceinline__ unsigned bcast_first(unsigned flag, unsigned val) {
    unsigned long long bal = __ballot(flag != 0);
    if (!bal) return 0u;
    return __shfl(val, __ffsll(bal) - 1, 64);
}

// packed u16 histogram with pad-every-16-words addressing
__device__ __forceinline__ void hadd(unsigned* h, unsigned b) {
    const unsigned w = b >> 1;
    atomicAdd(&h[w + (w >> 4)], (b & 1) ? 0x10000u : 1u);
}

// Wave0-only finish: 256-bin subhist over candidates, locate, tie-rank.
// hc must be pre-zeroed. Returns composite (low20<<12)|idx, or SENT, or 0.
template <bool fromTop>
__device__ unsigned wave_finish(unsigned* lds, unsigned m1, unsigned cnt) {
    const int lane = threadIdx.x & 63;
    unsigned* cand = lds + O_CAND;
    unsigned* hc   = lds + O_HC;
    unsigned* tiny = lds + O_TINY;
    if (m1 == 0) return 0u;
    if (cnt > CAP) return SENT;
    for (unsigned i = lane; i < cnt; i += 64) atomicAdd(&hc[cand[i] >> 24], 1u);
    unsigned hh[4];
#pragma unroll
    for (int i = 0; i < 4; ++i) hh[i] = hc[4 * lane + i];
    const unsigned s4 = hh[0] + hh[1] + hh[2] + hh[3];
    unsigned run2 = wscan_incl(s4) - s4;
    unsigned packed2 = 0;
#pragma unroll
    for (int i = 0; i < 4; ++i) {
        if (fromTop) {
            const unsigned suf = cnt - run2 - hh[i];
            if (suf < m1 && m1 <= suf + hh[i])
                packed2 = ((unsigned)(4 * lane + i) << 16) | (m1 - suf);
        } else {
            if (run2 < m1 && m1 <= run2 + hh[i])
                packed2 = ((unsigned)(4 * lane + i) << 16) | (m1 - run2);
        }
        run2 += hh[i];
    }
    packed2 = bcast_first(packed2, packed2);
    if (packed2 == 0) return 0u;
    const unsigned b2 = packed2 >> 16;
    const unsigned m2 = packed2 & 0xFFFFu;
    unsigned tc = 0;
    for (unsigned i = lane; i < cnt; i += 64) tc += ((cand[i] >> 24) == b2);
    const unsigned tincl = wscan_incl(tc);
    const unsigned c2 = __shfl((int)tincl, 63, 64);
    if (c2 > CAP2) return SENT;
    unsigned tpos = tincl - tc;
    for (unsigned i = lane; i < cnt; i += 64) {
        const unsigned cw = cand[i];
        if ((cw >> 24) == b2) tiny[tpos++] = cw;
    }
    unsigned hitf = 0, resv = 0;
    if ((unsigned)lane < c2) {
        const unsigned ci = tiny[lane];
        const unsigned di = fromTop ? (ci ^ 0xFFFu) : ci;
        unsigned r = 1;
        for (unsigned j = 0; j < c2; ++j) {
            const unsigned dj = fromTop ? (tiny[j] ^ 0xFFFu) : tiny[j];
            if (fromTop ? (dj > di) : (dj < di)) r++;
        }
        if (r == m2) { hitf = 1; resv = ci; }
    }
    return bcast_first(hitf, resv);
}

// Pathological fallback: bin-filtered counting rank over the LDS row.
template <bool fromTop>
__device__ void block_fallback(const unsigned* sx, unsigned b0, unsigned m1,
                               unsigned* res) {
    const int t = threadIdx.x;
    for (int j = t; j < HW; j += NT) {
        const unsigned k = sx[j] & M31;
        if ((k >> 20) != b0) continue;
        unsigned Ci = ((k & 0xFFFFFu) << 12) | (unsigned)j;
        if (fromTop) Ci ^= 0xFFFu;
        unsigned r = 1;
        for (int j2 = 0; j2 < HW; ++j2) {
            const unsigned k2 = sx[j2] & M31;
            if ((k2 >> 20) != b0) continue;
            unsigned Cj = ((k2 & 0xFFFFFu) << 12) | (unsigned)j2;
            if (fromTop) Cj ^= 0xFFFu;
            if (fromTop ? (Cj > Ci) : (Cj < Ci)) r++;
        }
        if (r == m1) res[0] = ((k & 0xFFFFFu) << 12) | (unsigned)j;
    }
}

extern "C" __global__ void __launch_bounds__(NT, 4)
topk_kernel(const float* __restrict__ x, float* __restrict__ out) {
    __shared__ unsigned lds[LDSW];
    __shared__ unsigned s_warp[2];
    __shared__ unsigned s_b[4];   // [0]=bin [1]=m1 [2]=result [3]=counter

    const int t = threadIdx.x;
    const int lane = t & 63;
    const int wid = t >> 6;
    const size_t row = blockIdx.x;
    const uint4* __restrict__ xin = (const uint4*)(x + row * HW);
    uint4* __restrict__ xo = (uint4*)(out + row * HW);
    uint4* s_x4 = (uint4*)(lds + O_X);
    const unsigned* sx = lds + O_X;
    const uint4 z4 = make_uint4(0u, 0u, 0u, 0u);
    const bool tail = (t < 16);

    // P0: clear hist region (1088 words = 272 uint4)
    {
        uint4* h4 = (uint4*)(lds + O_H);
        h4[t] = z4; h4[t + NT] = z4;
        if (tail) h4[t + 2 * NT] = z4;
    }
    __syncthreads();                                         // B1

    // P1: fused load: global -> (reg) -> LDS row + histogram (abs bits 30:20)
#pragma unroll
    for (int i = 0; i < 6; ++i) {
        const uint4 v = xin[t + NT * i];
        s_x4[t + NT * i] = v;
        hadd(lds + O_H, (v.x & M31) >> 20); hadd(lds + O_H, (v.y & M31) >> 20);
        hadd(lds + O_H, (v.z & M31) >> 20); hadd(lds + O_H, (v.w & M31) >> 20);
    }
    if (tail) {
        const uint4 v = xin[768 + t];
        s_x4[768 + t] = v;
        hadd(lds + O_H, (v.x & M31) >> 20); hadd(lds + O_H, (v.y & M31) >> 20);
        hadd(lds + O_H, (v.z & M31) >> 20); hadd(lds + O_H, (v.w & M31) >> 20);
    }
    __syncthreads();                                         // B2

    // P2: pull packed counts: thread t owns bins 16t..16t+15 = words 8t..8t+7
    // (padded addr = 8t + (t>>1) + j, contiguous); wave scan + publish
    unsigned cpk[8];
    {
        const unsigned a0 = 8u * (unsigned)t + ((unsigned)t >> 1);
#pragma unroll
        for (int j = 0; j < 8; ++j) cpk[j] = lds[O_H + a0 + j];
    }
    unsigned ssum = 0;
#pragma unroll
    for (int j = 0; j < 8; ++j) ssum += (cpk[j] & 0xFFFFu) + (cpk[j] >> 16);
    const unsigned Si = wscan_incl(ssum);
    if (lane == 63) s_warp[wid] = Si;
    __syncthreads();                                         // B3

    // P3: base; locate A (register CDF); zero counter; clear hc
    const unsigned base = (wid ? s_warp[0] : 0u) + Si - ssum;  // excl CDF bin 16t
    {
        unsigned run = base;
#pragma unroll
        for (int j = 0; j < 8; ++j) {
            const unsigned lo = cpk[j] & 0xFFFFu, hi = cpk[j] >> 16;
            unsigned suf = HW - run - lo;
            if (suf < KSEL && KSEL <= suf + lo) { s_b[0] = 16u * t + 2u * j; s_b[1] = KSEL - suf; }
            run += lo;
            suf = HW - run - hi;
            if (suf < KSEL && KSEL <= suf + hi) { s_b[0] = 16u * t + 2u * j + 1u; s_b[1] = KSEL - suf; }
            run += hi;
        }
    }
    if (t == 0) s_b[3] = 0;
    lds[O_HC + t] = 0; lds[O_HC + t + NT] = 0;
    __syncthreads();                                         // B4

    // P4: compact A from the LDS row
    auto compact_lds = [&](unsigned b0) {
        auto cput = [&](unsigned wv, unsigned idx) {
            const unsigned k = wv & M31;
            if ((k >> 20) == b0) {
                const unsigned p = atomicAdd(&s_b[3], 1u);
                if (p < CAP) lds[O_CAND + p] = ((k & 0xFFFFFu) << 12) | idx;
            }
        };
#pragma unroll
        for (int i = 0; i < 6; ++i) {
            const uint4 v = s_x4[t + NT * i];
            const unsigned i0 = 4u * (unsigned)(t + NT * i);
            cput(v.x, i0); cput(v.y, i0 + 1u); cput(v.z, i0 + 2u); cput(v.w, i0 + 3u);
        }
        if (tail) {
            const uint4 v = s_x4[768 + t];
            const unsigned i0 = 4u * (unsigned)(768 + t);
            cput(v.x, i0); cput(v.y, i0 + 1u); cput(v.z, i0 + 2u); cput(v.w, i0 + 3u);
        }
    };
    const unsigned b0A = s_b[0];
    const unsigned m1A = s_b[1];
    compact_lds(b0A);
    __syncthreads();                                         // B5

    // P5: wave0 finish A
    if (wid == 0) {
        const unsigned r = wave_finish<true>(lds, m1A, s_b[3]);
        if (lane == 0) s_b[2] = r;
    }
    __syncthreads();                                         // B6
    unsigned compA = s_b[2];
    if (compA == SENT) {
        block_fallback<true>(sx, b0A, m1A, &s_b[2]);
        __syncthreads();
        compA = s_b[2];
    }
    const unsigned tIdx = compA & 0xFFFu;

    // P6: locate B (cpk still live); zero counter; clear hc; sentinel
    {
        unsigned run = base;
#pragma unroll
        for (int j = 0; j < 8; ++j) {
            const unsigned lo = cpk[j] & 0xFFFFu, hi = cpk[j] >> 16;
            if (run < tIdx && tIdx <= run + lo) { s_b[0] = 16u * t + 2u * j; s_b[1] = tIdx - run; }
            run += lo;
            if (run < tIdx && tIdx <= run + hi) { s_b[0] = 16u * t + 2u * j + 1u; s_b[1] = tIdx - run; }
            run += hi;
        }
    }
    if (t == 0) {
        s_b[3] = 0;
        if (tIdx == 0) { s_b[0] = 0; s_b[1] = 0; }   // keep-nothing (benign)
    }
    lds[O_HC + t] = 0; lds[O_HC + t + NT] = 0;
    __syncthreads();                                         // B7

    // P7: compact B from the LDS row
    const unsigned b0B = s_b[0];
    const unsigned m1B = s_b[1];
    compact_lds(b0B);
    __syncthreads();                                         // B8

    // P8: wave0 finish B
    if (wid == 0) {
        const unsigned r = wave_finish<false>(lds, m1B, s_b[3]);
        if (lane == 0) s_b[2] = r;
    }
    __syncthreads();                                         // B9
    unsigned compB = s_b[2];
    if (compB == SENT) {
        block_fallback<false>(sx, b0B, m1B, &s_b[2]);
        __syncthreads();
        compB = s_b[2];
    }
    const unsigned KB = (b0B << 20) | (compB >> 12);
    const unsigned eB = compB & 0xFFFu;

    // P9: mask + store from the LDS row
    {
        auto msk = [&](unsigned wv, unsigned idx) -> unsigned {
            const unsigned k = wv & M31;
            return (k < KB || (k == KB && idx <= eB)) ? wv : 0u;
        };
#pragma unroll
        for (int i = 0; i < 6; ++i) {
            uint4 v = s_x4[t + NT * i];
            const unsigned i0 = 4u * (unsigned)(t + NT * i);
            v.x = msk(v.x, i0); v.y = msk(v.y, i0 + 1u);
            v.z = msk(v.z, i0 + 2u); v.w = msk(v.w, i0 + 3u);
            xo[t + NT * i] = v;
        }
        if (tail) {
            uint4 v = s_x4[768 + t];
            const unsigned i0 = 4u * (unsigned)(768 + t);
            v.x = msk(v.x, i0); v.y = msk(v.y, i0 + 1u);
            v.z = msk(v.z, i0 + 2u); v.w = msk(v.w, i0 + 3u);
            xo[768 + t] = v;
        }
    }
}

extern "C" void kernel_launch(void* const* d_in, const int* in_sizes, int n_in,
                              void* d_out, int out_size, void* d_ws, size_t ws_size,
                              hipStream_t stream) {
    const float* x = (const float*)d_in[0];
    float* out = (float*)d_out;
    const int rows = in_sizes[0] / HW;          // 8192
    topk_kernel<<<dim3(rows), dim3(NT), 0, stream>>>(x, out);
}

// Round 17
// 59.836 us; speedup vs baseline: 1.2496x; 1.2496x over previous
//
#include <hip/hip_runtime.h>
#include <stdint.h>

// TopKLayer quirky sparse_hw: per row (3136 elems), t = spatial index of the
// k-th largest |x| (k=313, ties ascending index); keep the t smallest-|x|
// elements (stable). 128-THREAD BLOCK PER ROW: row pinned in registers via
// asm keep-alive fence (no remat re-loads -> no L2/HBM re-streams), 4.2 KB
// LDS (packed-u16 2048-bin hist reused as cand/hc/tiny), VGPR capped by
// __launch_bounds__(128,6). BEST MEASURED: 59.6 us wall (R12).

#define HW    3136
#define NT    128
#define KSEL  313u
#define CAP   320u       // candidate bin capacity (stat max ~190)
#define CAP2  64u        // tie-set capacity
#define O_CAND 0         // overlay regions in s_h (hist dead after CDF pull)
#define O_HC   384
#define O_TINY 704
#define M31   0x7fffffffu
#define SENT  0xFFFFFFFFu

__device__ __forceinline__ unsigned wscan_incl(unsigned v) {
    const int lane = threadIdx.x & 63;
#pragma unroll
    for (int d = 1; d < 64; d <<= 1) {
        unsigned o = __shfl_up(v, d, 64);
        if (lane >= d) v += o;
    }
    return v;
}

__device__ __forceinline__ unsigned bcast_first(unsigned flag, unsigned val) {
    unsigned long long bal = __ballot(flag != 0);
    if (!bal) return 0u;
    return __shfl(val, __ffsll(bal) - 1, 64);
}

// packed u16 histogram: adjacent bins share one word (word = bin>>1)
__device__ __forceinline__ void hadd(unsigned* h, unsigned b) {
    atomicAdd(&h[b >> 1], (b & 1) ? 0x10000u : 1u);
}

// One-wave finish: subhist over compacted candidates, locate, tie-rank.
// Reads br[1]=m1, br[3]=cnt. Writes br[2] UNCONDITIONALLY (SENT -> fallback).
template <bool fromTop>
__device__ void wave_finish(unsigned* hr, unsigned* br) {
    const int lane = threadIdx.x & 63;
    const unsigned cnt = br[3];
    const unsigned m1  = br[1];
    unsigned* cand = hr + O_CAND;
    unsigned* hc   = hr + O_HC;
    unsigned* tiny = hr + O_TINY;
    if (cnt > CAP) { if (lane == 0) br[2] = (m1 == 0) ? 0u : SENT; return; }
    for (unsigned i = lane; i < cnt; i += 64) atomicAdd(&hc[cand[i] >> 24], 1u);
    unsigned hh[4];
#pragma unroll
    for (int i = 0; i < 4; ++i) hh[i] = hc[4 * lane + i];
    const unsigned s4 = hh[0] + hh[1] + hh[2] + hh[3];
    unsigned run2 = wscan_incl(s4) - s4;
    unsigned packed2 = 0;
#pragma unroll
    for (int i = 0; i < 4; ++i) {
        if (fromTop) {
            const unsigned suf = cnt - run2 - hh[i];
            if (suf < m1 && m1 <= suf + hh[i])
                packed2 = ((unsigned)(4 * lane + i) << 16) | (m1 - suf);
        } else {
            if (run2 < m1 && m1 <= run2 + hh[i])
                packed2 = ((unsigned)(4 * lane + i) << 16) | (m1 - run2);
        }
        run2 += hh[i];
    }
    packed2 = bcast_first(packed2, packed2);
    if (packed2 == 0) { if (lane == 0) br[2] = 0u; return; }  // m1==0 sentinel
    const unsigned b2 = packed2 >> 16;
    const unsigned m2 = packed2 & 0xFFFFu;
    unsigned tc = 0;
    for (unsigned i = lane; i < cnt; i += 64) tc += ((cand[i] >> 24) == b2);
    const unsigned tincl = wscan_incl(tc);
    const unsigned c2 = __shfl((int)tincl, 63, 64);
    if (c2 > CAP2) { if (lane == 0) br[2] = SENT; return; }
    unsigned tpos = tincl - tc;
    for (unsigned i = lane; i < cnt; i += 64) {
        const unsigned cw = cand[i];
        if ((cw >> 24) == b2) tiny[tpos++] = cw;
    }
    unsigned hitf = 0, resv = 0;
    if ((unsigned)lane < c2) {
        const unsigned ci = tiny[lane];
        const unsigned di = fromTop ? (ci ^ 0xFFFu) : ci;
        unsigned r = 1;
        for (unsigned j = 0; j < c2; ++j) {
            const unsigned dj = fromTop ? (tiny[j] ^ 0xFFFu) : tiny[j];
            if (fromTop ? (dj > di) : (dj < di)) r++;
        }
        if (r == m2) { hitf = 1; resv = ci; }
    }
    resv = bcast_first(hitf, resv);
    if (lane == 0) br[2] = resv;
}

// Pathological fallback: bin-filtered counting rank over global row.
template <bool fromTop>
__device__ void block_fallback(const unsigned* __restrict__ gx, unsigned* br) {
    const unsigned b0 = br[0], m1 = br[1];
    const int t = threadIdx.x;
    for (int j = t; j < HW; j += NT) {
        const unsigned k = gx[j] & M31;
        if ((k >> 20) != b0) continue;
        unsigned Ci = ((k & 0xFFFFFu) << 12) | (unsigned)j;
        if (fromTop) Ci ^= 0xFFFu;
        unsigned r = 1;
        for (int j2 = 0; j2 < HW; ++j2) {
            const unsigned k2 = gx[j2] & M31;
            if ((k2 >> 20) != b0) continue;
            unsigned Cj = ((k2 & 0xFFFFFu) << 12) | (unsigned)j2;
            if (fromTop) Cj ^= 0xFFFu;
            if (fromTop ? (Cj > Ci) : (Cj < Ci)) r++;
        }
        if (r == m1) br[2] = ((k & 0xFFFFFu) << 12) | (unsigned)j;
    }
}

extern "C" __global__ void __launch_bounds__(NT, 6)
topk_kernel(const float* __restrict__ x, float* __restrict__ out) {
    __shared__ unsigned s_h[1024];   // 4096 B: packed hist -> cand/hc/tiny
    __shared__ unsigned s_warp[2];
    __shared__ unsigned s_b[4];      // [0]=bin [1]=m1 [2]=result [3]=counter

    const int t = threadIdx.x;
    const int lane = t & 63;
    const int wid = t >> 6;
    const size_t row = blockIdx.x;
    const uint4* __restrict__ xin = (const uint4*)(x + row * HW);
    uint4* __restrict__ xo = (uint4*)(out + row * HW);
    const unsigned* __restrict__ gx = (const unsigned*)xin;
    const uint4 z4 = make_uint4(0u, 0u, 0u, 0u);

    // load row into registers; asm fence blocks rematerialization-as-reload
    uint4 v[6];
#pragma unroll
    for (int i = 0; i < 6; ++i) v[i] = xin[t + NT * i];
    uint4 vt = (t < 16) ? xin[768 + t] : z4;
#pragma unroll
    for (int i = 0; i < 6; ++i)
        asm volatile("" : "+v"(v[i].x), "+v"(v[i].y), "+v"(v[i].z), "+v"(v[i].w));
    asm volatile("" : "+v"(vt.x), "+v"(vt.y), "+v"(vt.z), "+v"(vt.w));

    // P0: clear hist (256 uint4 = 1024 words)
    ((uint4*)s_h)[t] = z4;
    ((uint4*)s_h)[t + NT] = z4;
    __syncthreads();

    // P1: 2048-bin packed-u16 histogram from registers (abs bits 30:20)
#pragma unroll
    for (int i = 0; i < 6; ++i) {
        hadd(s_h, (v[i].x & M31) >> 20); hadd(s_h, (v[i].y & M31) >> 20);
        hadd(s_h, (v[i].z & M31) >> 20); hadd(s_h, (v[i].w & M31) >> 20);
    }
    if (t < 16) {
        hadd(s_h, (vt.x & M31) >> 20); hadd(s_h, (vt.y & M31) >> 20);
        hadd(s_h, (vt.z & M31) >> 20); hadd(s_h, (vt.w & M31) >> 20);
    }
    __syncthreads();

    // P2: pull packed counts (thread t owns bins 16t..16t+15); wave sums
    const uint4 w0 = ((const uint4*)s_h)[2 * t];
    const uint4 w1 = ((const uint4*)s_h)[2 * t + 1];
    unsigned cpk[8] = {w0.x, w0.y, w0.z, w0.w, w1.x, w1.y, w1.z, w1.w};
    unsigned ssum = 0;
#pragma unroll
    for (int j = 0; j < 8; ++j) ssum += (cpk[j] & 0xFFFFu) + (cpk[j] >> 16);
    const unsigned Si = wscan_incl(ssum);
    if (lane == 63) s_warp[wid] = Si;
    __syncthreads();

    // P3: base (excl CDF of bin 16t); locate A; zero counter; clear hc
    const unsigned base = Si - ssum + (wid ? s_warp[0] : 0u);
    {
        unsigned run = base;
#pragma unroll
        for (int j = 0; j < 8; ++j) {
            const unsigned lo = cpk[j] & 0xFFFFu, hi = cpk[j] >> 16;
            unsigned suf = HW - run - lo;
            if (suf < KSEL && KSEL <= suf + lo) { s_b[0] = 16u * t + 2u * j; s_b[1] = KSEL - suf; }
            run += lo;
            suf = HW - run - hi;
            if (suf < KSEL && KSEL <= suf + hi) { s_b[0] = 16u * t + 2u * j + 1u; s_b[1] = KSEL - suf; }
            run += hi;
        }
    }
    if (t == 0) s_b[3] = 0;
    s_h[O_HC + t] = 0; s_h[O_HC + t + NT] = 0;
    __syncthreads();

    // P4: compact A from registers
    auto compact_regs = [&](unsigned b0) {
        auto cput = [&](unsigned wv, unsigned idx) {
            const unsigned k = wv & M31;
            if ((k >> 20) == b0) {
                const unsigned p = atomicAdd(&s_b[3], 1u);
                if (p < CAP) s_h[O_CAND + p] = ((k & 0xFFFFFu) << 12) | idx;
            }
        };
#pragma unroll
        for (int i = 0; i < 6; ++i) {
            const unsigned i0 = 4u * (unsigned)(t + NT * i);
            cput(v[i].x, i0); cput(v[i].y, i0 + 1u);
            cput(v[i].z, i0 + 2u); cput(v[i].w, i0 + 3u);
        }
        if (t < 16) {
            const unsigned i0 = 4u * (unsigned)(768 + t);
            cput(vt.x, i0); cput(vt.y, i0 + 1u);
            cput(vt.z, i0 + 2u); cput(vt.w, i0 + 3u);
        }
    };
    compact_regs(s_b[0]);
    __syncthreads();

    // P5: wave0 finish A
    if (wid == 0) wave_finish<true>(s_h, s_b);
    __syncthreads();

    unsigned compA = s_b[2];
    if (compA == SENT) {
        block_fallback<true>(gx, s_b);
        __syncthreads();
        compA = s_b[2];
    }
    const unsigned tIdx = compA & 0xFFFu;

    // P6: locate B; zero counter; clear hc; keep-nothing sentinel
    {
        unsigned run = base;
#pragma unroll
        for (int j = 0; j < 8; ++j) {
            const unsigned lo = cpk[j] & 0xFFFFu, hi = cpk[j] >> 16;
            if (run < tIdx && tIdx <= run + lo) { s_b[0] = 16u * t + 2u * j; s_b[1] = tIdx - run; }
            run += lo;
            if (run < tIdx && tIdx <= run + hi) { s_b[0] = 16u * t + 2u * j + 1u; s_b[1] = tIdx - run; }
            run += hi;
        }
    }
    if (t == 0) {
        s_b[3] = 0;
        if (tIdx == 0) { s_b[0] = 0; s_b[1] = 0; }   // keep-nothing (benign)
    }
    s_h[O_HC + t] = 0; s_h[O_HC + t + NT] = 0;
    __syncthreads();

    // P7: compact B from registers
    const unsigned b0B = s_b[0];
    compact_regs(b0B);
    __syncthreads();

    // P8: wave0 finish B
    if (wid == 0) wave_finish<false>(s_h, s_b);
    __syncthreads();

    unsigned compB = s_b[2];
    if (compB == SENT) {
        block_fallback<false>(gx, s_b);
        __syncthreads();
        compB = s_b[2];
    }
    const unsigned KB = (b0B << 20) | (compB >> 12);
    const unsigned eB = compB & 0xFFFu;

    // P9: mask + store from registers
    {
        auto msk = [&](unsigned wv, unsigned idx) -> unsigned {
            const unsigned k = wv & M31;
            return (k < KB || (k == KB && idx <= eB)) ? wv : 0u;
        };
#pragma unroll
        for (int i = 0; i < 6; ++i) {
            const unsigned i0 = 4u * (unsigned)(t + NT * i);
            uint4 o = v[i];
            o.x = msk(o.x, i0); o.y = msk(o.y, i0 + 1u);
            o.z = msk(o.z, i0 + 2u); o.w = msk(o.w, i0 + 3u);
            xo[t + NT * i] = o;
        }
        if (t < 16) {
            const unsigned i0 = 4u * (unsigned)(768 + t);
            uint4 o = vt;
            o.x = msk(o.x, i0); o.y = msk(o.y, i0 + 1u);
            o.z = msk(o.z, i0 + 2u); o.w = msk(o.w, i0 + 3u);
            xo[768 + t] = o;
        }
    }
}

extern "C" void kernel_launch(void* const* d_in, const int* in_sizes, int n_in,
                              void* d_out, int out_size, void* d_ws, size_t ws_size,
                              hipStream_t stream) {
    const float* x = (const float*)d_in[0];
    float* out = (float*)d_out;
    const int rows = in_sizes[0] / HW;          // 8192
    topk_kernel<<<dim3(rows), dim3(NT), 0, stream>>>(x, out);
}